// Round 20
// baseline (178.817 us; speedup 1.0000x reference)
//
#include <hip/hip_runtime.h>
#include <float.h>

typedef __bf16 bf16;
typedef __bf16 bf16x8 __attribute__((ext_vector_type(8)));
typedef float f32x4 __attribute__((ext_vector_type(4)));

#define GAS __attribute__((address_space(1)))
#define LAS __attribute__((address_space(3)))

__device__ __forceinline__ void gload_lds16(const void* g, void* l) {
  __builtin_amdgcn_global_load_lds((const GAS unsigned int*)g, (LAS unsigned int*)l, 16, 0, 0);
}

// ---------------------------------------------------------------------------
// FUSED Q-projection GEMM + attention — 4 blocks/CU x 4 waves.
// BM=64 x BN=128 (2 heads), 256 threads (2M x 2N waves, wave tile 32x64),
// BK=32 ring-2: main LDS 24 KB; epilogue adds Ep 16 KB (K then V,
// time-shared) -> 40 KB total -> 4 blocks/CU. Grid 4x256 = 1024 = exactly
// 4/CU: same 16 waves/CU as R17 but 4 independent barrier domains (R10's
// confirmed TLP mechanism at finer granularity). Math bit-identical.
// ---------------------------------------------------------------------------
__global__ __launch_bounds__(256, 4) void qattn(
    const bf16* __restrict__ xn, const bf16* __restrict__ wqT,
    const bf16* __restrict__ kvb, const int* __restrict__ mk,
    const int* __restrict__ endw, bf16* __restrict__ aob) {
  constexpr int K = 2048;
  __shared__ __align__(16) bf16 SM[12288];  // 24 KB: A ring 8KB + B ring 16KB
  __shared__ __align__(16) bf16 Ep[8192];   // 16 KB: K then V (time-shared)
  const int tid = threadIdx.x, lane = tid & 63;
  const int w = tid >> 6, wr = w >> 1, wc = w & 1;  // 2M x 2N
  const int g = lane >> 4, fr = lane & 15;

  // bijective XCD-chunked swizzle (nwg = 1024 -> qq = 128)
  const int gx = gridDim.x;
  int lid = blockIdx.y * gx + blockIdx.x;
  lid = ((lid & 7) << 7) | (lid >> 3);
  const int bx = lid % gx, by = lid / gx;
  const size_t m0 = (size_t)by * 64;
  const int n0 = bx * 128;  // heads 2*bx, 2*bx+1
  const int b = by >> 6;    // batch (64 token-tiles of 64 per batch)

  const int nt = K >> 5;  // 64 tiles of BK=32
  const int srow = tid >> 2, sslot = tid & 3;

  auto Abuf = [&](int s) { return SM + s * 2048; };         // 64x32 each
  auto Bbuf = [&](int s) { return SM + 4096 + s * 4096; };  // 128x32 each

  f32x4 acc[2][4] = {};

  auto stage = [&](int t) {
    const int s = t & 1;
    const int kt = t << 5;
    // A: 64 rows x 32 cols = 256 16B units, 1/thread
    {
      const int r = srow;  // tid>>2 in 0..63
      gload_lds16(xn + (m0 + r) * (size_t)K + kt + ((sslot ^ (r & 3)) << 3),
                  Abuf(s) + tid * 8);
    }
    // B: 128 rows x 32 cols = 512 units, 2/thread
#pragma unroll
    for (int j = 0; j < 2; ++j) {
      const int idx = j * 256 + tid;
      const int r = idx >> 2, sl = idx & 3;
      gload_lds16(wqT + (size_t)(n0 + r) * K + kt + ((sl ^ (r & 3)) << 3),
                  Bbuf(s) + idx * 8);
    }
  };
  auto rdA = [&](int s, int mi) {
    const int r = wr * 32 + mi * 16 + fr;
    return *(const bf16x8*)(Abuf(s) + r * 32 + ((g ^ (r & 3)) << 3));
  };
  auto rdB = [&](int s, int ni) {
    const int r = wc * 64 + ni * 16 + fr;
    return *(const bf16x8*)(Bbuf(s) + r * 32 + ((g ^ (r & 3)) << 3));
  };
  auto compute = [&](int t) {
    const int s = t & 1;
    bf16x8 bv[4];
#pragma unroll
    for (int ni = 0; ni < 4; ++ni) bv[ni] = rdB(s, ni);
    __builtin_amdgcn_s_setprio(1);
#pragma unroll
    for (int mi = 0; mi < 2; ++mi) {
      const bf16x8 av = rdA(s, mi);
#pragma unroll
      for (int ni = 0; ni < 4; ++ni)
        acc[mi][ni] = __builtin_amdgcn_mfma_f32_16x16x32_bf16(
            av, bv[ni], acc[mi][ni], 0, 0, 0);
    }
    __builtin_amdgcn_s_setprio(0);
  };

  stage(0);
  for (int t = 0; t < nt; ++t) {
    __syncthreads();
    if (t + 1 < nt) stage(t + 1);
    compute(t);
  }

  // ======== attention epilogue ========
  __syncthreads();  // main-loop LDS reads done

  bf16* QP = SM + w * 2048;  // wave-private [32 rows][64 cols] swizzled

  // Q acc -> QP
#pragma unroll
  for (int mi = 0; mi < 2; ++mi)
#pragma unroll
    for (int ni = 0; ni < 4; ++ni)
#pragma unroll
      for (int rg = 0; rg < 4; ++rg) {
        const int row = mi * 16 + g * 4 + rg, col = ni * 16 + fr;
        QP[row * 64 + (((col >> 3) ^ (row & 7)) << 3) + (col & 7)] =
            (bf16)acc[mi][ni][rg];
      }

  // K stage into Ep ([2 heads][64 l][64 dh], swizzled): 1024 units, 4/thread
#pragma unroll
  for (int j = 0; j < 4; ++j) {
    const int idx = j * 256 + tid;
    const int head = idx >> 9, l = (idx >> 3) & 63, sl = idx & 7;
    gload_lds16(kvb + (size_t)(b * 64 + l) * 1024 + (2 * bx + head) * 64 +
                    ((sl ^ (l & 7)) << 3),
                Ep + idx * 8);
  }
  asm volatile("s_waitcnt vmcnt(0)" ::: "memory");
  __syncthreads();

  // S = Q @ K^T
  f32x4 sacc[2][4] = {};
#pragma unroll
  for (int ks = 0; ks < 2; ++ks) {
    bf16x8 aq[2], bk[4];
#pragma unroll
    for (int mi = 0; mi < 2; ++mi) {
      const int r = mi * 16 + fr;
      aq[mi] = *(const bf16x8*)&QP[r * 64 + ((((ks << 2) | g) ^ (r & 7)) << 3)];
    }
#pragma unroll
    for (int ni = 0; ni < 4; ++ni) {
      const int l = ni * 16 + fr;
      bk[ni] = *(const bf16x8*)&Ep[wc * 4096 + l * 64 +
                                   ((((ks << 2) | g) ^ (l & 7)) << 3)];
    }
#pragma unroll
    for (int mi = 0; mi < 2; ++mi)
#pragma unroll
      for (int ni = 0; ni < 4; ++ni)
        sacc[mi][ni] = __builtin_amdgcn_mfma_f32_16x16x32_bf16(
            aq[mi], bk[ni], sacc[mi][ni], 0, 0, 0);
  }

  __syncthreads();  // all waves done reading Ep-K

  // V (transposed) overwrites Ep
#pragma unroll
  for (int j = 0; j < 4; ++j) {
    const int idx = j * 256 + tid;
    const int head = idx >> 9, l = (idx >> 3) & 63, sg = idx & 7;
    bf16x8 vv = *(const bf16x8*)&kvb[(size_t)(b * 64 + l) * 1024 + 512 +
                                     (2 * bx + head) * 64 + sg * 8];
#pragma unroll
    for (int e = 0; e < 8; ++e) {
      const int dh = sg * 8 + e;
      Ep[head * 4096 + dh * 64 + (((l >> 3) ^ (dh & 7)) << 3) + (l & 7)] =
          vv[e];
    }
  }

  // mask + softmax (register-only) + P -> QP (wave-private)
#pragma unroll
  for (int mi = 0; mi < 2; ++mi) {
    const int4 ev4 = *(const int4*)&endw[m0 + wr * 32 + mi * 16 + g * 4];
    const int ev[4] = {ev4.x, ev4.y, ev4.z, ev4.w};
    float p[4][4];
#pragma unroll
    for (int ni = 0; ni < 4; ++ni) {
      const int l = ni * 16 + fr;
      const bool mv = (mk[b * 64 + l] != 0);
#pragma unroll
      for (int rg = 0; rg < 4; ++rg)
        p[ni][rg] = (mv && (l < ev[rg])) ? sacc[mi][ni][rg] : -FLT_MAX;
    }
#pragma unroll
    for (int rg = 0; rg < 4; ++rg) {
      float m = fmaxf(fmaxf(p[0][rg], p[1][rg]), fmaxf(p[2][rg], p[3][rg]));
      m = fmaxf(m, __shfl_xor(m, 1));
      m = fmaxf(m, __shfl_xor(m, 2));
      m = fmaxf(m, __shfl_xor(m, 4));
      m = fmaxf(m, __shfl_xor(m, 8));
      float sum = 0.f;
#pragma unroll
      for (int ni = 0; ni < 4; ++ni) {
        p[ni][rg] = __expf(p[ni][rg] - m);
        sum += p[ni][rg];
      }
      sum += __shfl_xor(sum, 1);
      sum += __shfl_xor(sum, 2);
      sum += __shfl_xor(sum, 4);
      sum += __shfl_xor(sum, 8);
      const float inv = 1.f / sum;
#pragma unroll
      for (int ni = 0; ni < 4; ++ni) p[ni][rg] *= inv;
    }
#pragma unroll
    for (int ni = 0; ni < 4; ++ni) {
      const int l = ni * 16 + fr;
#pragma unroll
      for (int rg = 0; rg < 4; ++rg) {
        const int row = mi * 16 + g * 4 + rg;
        QP[row * 64 + (((l >> 3) ^ (row & 7)) << 3) + (l & 7)] =
            (bf16)p[ni][rg];
      }
    }
  }

  __syncthreads();  // Ep-V visible to all

  // O = P @ V
  f32x4 oacc[2][4] = {};
#pragma unroll
  for (int ks = 0; ks < 2; ++ks) {
    bf16x8 pa[2], bv[4];
#pragma unroll
    for (int mi = 0; mi < 2; ++mi) {
      const int r = mi * 16 + fr;
      pa[mi] = *(const bf16x8*)&QP[r * 64 + ((((ks << 2) | g) ^ (r & 7)) << 3)];
    }
#pragma unroll
    for (int nd = 0; nd < 4; ++nd) {
      const int dh = nd * 16 + fr;
      bv[nd] = *(const bf16x8*)&Ep[wc * 4096 + dh * 64 +
                                   ((((ks << 2) | g) ^ (dh & 7)) << 3)];
    }
#pragma unroll
    for (int mi = 0; mi < 2; ++mi)
#pragma unroll
      for (int nd = 0; nd < 4; ++nd)
        oacc[mi][nd] = __builtin_amdgcn_mfma_f32_16x16x32_bf16(
            pa[mi], bv[nd], oacc[mi][nd], 0, 0, 0);
  }
#pragma unroll
  for (int mi = 0; mi < 2; ++mi)
#pragma unroll
    for (int nd = 0; nd < 4; ++nd)
#pragma unroll
      for (int rg = 0; rg < 4; ++rg) {
        const size_t t = m0 + wr * 32 + mi * 16 + g * 4 + rg;
        aob[t * 512 + (2 * bx + wc) * 64 + nd * 16 + fr] =
            (bf16)oacc[mi][nd][rg];
      }
}

// ---------------------------------------------------------------------------
// m97-style 128x128 GEMM, BK=32, 16 KB LDS -> multi-block/CU TLP overlap.
// Used for KV projection and the output projection.
// ---------------------------------------------------------------------------
template <int OUT_BF16>
__global__ __launch_bounds__(256, 2) void gemm_bt(
    const bf16* __restrict__ A, const bf16* __restrict__ Bt,
    void* __restrict__ Cv, int M, int N, int K) {
  __shared__ bf16 As[128 * 32];
  __shared__ bf16 Bs[128 * 32];
  const int tid = threadIdx.x;
  const int lane = tid & 63, w = tid >> 6;
  const int wr = w >> 1, wc = w & 1;

  const int gx = gridDim.x;
  const int nwg = gx * gridDim.y;
  int lid = blockIdx.y * gx + blockIdx.x;
  {
    const int qq = nwg >> 3, rr = nwg & 7;
    const int xcd = lid & 7, pos = lid >> 3;
    lid = (xcd < rr ? xcd * (qq + 1) : rr * (qq + 1) + (xcd - rr) * qq) + pos;
  }
  const int bx = lid % gx, by = lid / gx;
  const size_t m0 = (size_t)by * 128, n0 = (size_t)bx * 128;

  const int srow = lane >> 2, sslot = lane & 3;
  const int g = lane >> 4, fr = lane & 15;

  f32x4 acc[4][4] = {};

  for (int kt = 0; kt < K; kt += 32) {
    __syncthreads();
#pragma unroll
    for (int j = 0; j < 2; ++j) {
      const int c = 2 * w + j;
      const int r = c * 16 + srow;
      const int ks = (sslot ^ (r & 3)) << 3;
      gload_lds16(A + (m0 + r) * K + kt + ks, &As[c * 512]);
      gload_lds16(Bt + (n0 + r) * K + kt + ks, &Bs[c * 512]);
    }
    __syncthreads();
    bf16x8 av[4], bv[4];
#pragma unroll
    for (int mi = 0; mi < 4; ++mi) {
      const int r = wr * 64 + mi * 16 + fr;
      av[mi] = *(const bf16x8*)&As[r * 32 + ((g ^ (r & 3)) << 3)];
    }
#pragma unroll
    for (int ni = 0; ni < 4; ++ni) {
      const int r = wc * 64 + ni * 16 + fr;
      bv[ni] = *(const bf16x8*)&Bs[r * 32 + ((g ^ (r & 3)) << 3)];
    }
#pragma unroll
    for (int mi = 0; mi < 4; ++mi)
#pragma unroll
      for (int ni = 0; ni < 4; ++ni)
        acc[mi][ni] = __builtin_amdgcn_mfma_f32_16x16x32_bf16(
            av[mi], bv[ni], acc[mi][ni], 0, 0, 0);
  }

#pragma unroll
  for (int mi = 0; mi < 4; ++mi)
#pragma unroll
    for (int ni = 0; ni < 4; ++ni)
#pragma unroll
      for (int rg = 0; rg < 4; ++rg) {
        const size_t row = m0 + wr * 64 + mi * 16 + g * 4 + rg;
        const size_t col = n0 + wc * 64 + ni * 16 + fr;
        if (OUT_BF16)
          ((bf16*)Cv)[row * (size_t)N + col] = (bf16)acc[mi][ni][rg];
        else
          ((float*)Cv)[row * (size_t)N + col] = acc[mi][ni][rg];
      }
}

// ---------------------------------------------------------------------------
// Coalesced 64x64 LDS-tiled transpose: dst[C][R] = src[R][C] * scale (bf16)
// ---------------------------------------------------------------------------
__device__ __forceinline__ void transp64(const float* __restrict__ src,
                                         bf16* __restrict__ dst, int R, int C,
                                         float scale, int tile, float* lds) {
  const int tilesC = C >> 6;
  const int tr = tile / tilesC, tc = tile % tilesC;
  const int r0 = tr << 6, c0 = tc << 6;
  const int tid = threadIdx.x;
  const int lr = tid >> 6, lc = tid & 63;
#pragma unroll
  for (int j = 0; j < 16; ++j) {
    const int r = j * 4 + lr;
    lds[r * 65 + lc] = src[(size_t)(r0 + r) * C + c0 + lc];
  }
  __syncthreads();
#pragma unroll
  for (int j = 0; j < 16; ++j) {
    const int rr = j * 4 + lr;  // dst row = src col
    dst[(size_t)(c0 + rr) * R + r0 + lc] = (bf16)(lds[lc * 65 + rr] * scale);
  }
}

// ---------------------------------------------------------------------------
// Mega prep kernel: one launch, block-range partitioned (baseline layout).
// ---------------------------------------------------------------------------
__global__ __launch_bounds__(256) void prep_all(
    const float* __restrict__ x, const float* __restrict__ gamma,
    const float* __restrict__ beta, bf16* __restrict__ xn,
    const float* __restrict__ Wq, bf16* __restrict__ wqT,
    const float* __restrict__ Wkv, bf16* __restrict__ wkvT,
    const float* __restrict__ Wout, bf16* __restrict__ woT,
    const float* __restrict__ media, bf16* __restrict__ medb,
    const int* __restrict__ mloc, int* __restrict__ endw,
    const unsigned char* __restrict__ mraw, int* __restrict__ mk) {
  __shared__ float shf[64 * 65];
  const int blk = blockIdx.x, tid = threadIdx.x;

  if (blk < 16384) {
    const size_t base = (size_t)blk * 2048 + tid * 8;
    f32x4 v0 = *(const f32x4*)(x + base);
    f32x4 v1 = *(const f32x4*)(x + base + 4);
    float s = 0.f, q2 = 0.f;
#pragma unroll
    for (int j = 0; j < 4; ++j) {
      s += v0[j] + v1[j];
      q2 += v0[j] * v0[j] + v1[j] * v1[j];
    }
    for (int off = 32; off > 0; off >>= 1) {
      s += __shfl_down(s, off);
      q2 += __shfl_down(q2, off);
    }
    const int lane = tid & 63, wv = tid >> 6;
    if (lane == 0) { shf[wv] = s; shf[4 + wv] = q2; }
    __syncthreads();
    s = shf[0] + shf[1] + shf[2] + shf[3];
    q2 = shf[4] + shf[5] + shf[6] + shf[7];
    const float mu = s * (1.f / 2048.f);
    const float var = q2 * (1.f / 2048.f) - mu * mu;
    const float rs = rsqrtf(var + 1e-5f);
    f32x4 g0 = *(const f32x4*)(gamma + tid * 8);
    f32x4 g1 = *(const f32x4*)(gamma + tid * 8 + 4);
    f32x4 b0 = *(const f32x4*)(beta + tid * 8);
    f32x4 b1 = *(const f32x4*)(beta + tid * 8 + 4);
    bf16x8 o;
#pragma unroll
    for (int j = 0; j < 4; ++j) {
      o[j] = (bf16)((v0[j] - mu) * rs * g0[j] + b0[j]);
      o[4 + j] = (bf16)((v1[j] - mu) * rs * g1[j] + b1[j]);
    }
    *(bf16x8*)(xn + base) = o;
  } else if (blk < 16640) {
    transp64(Wq, wqT, 2048, 512, 0.125f, blk - 16384, shf);
  } else if (blk < 16896) {
    transp64(Wkv, wkvT, 1024, 1024, 1.f, blk - 16640, shf);
  } else if (blk < 17152) {
    transp64(Wout, woT, 512, 2048, 1.f, blk - 16896, shf);
  } else if (blk < 18176) {
    const int i = (blk - 17152) * 256 + tid;
    medb[i] = (bf16)media[i];
  } else if (blk < 18180) {
    int* part = (int*)shf;
    const int b = blk - 18176;
    int loc[16];
    int s = 0;
    const int base = b * 4096 + tid * 16;
#pragma unroll
    for (int j = 0; j < 16; ++j) {
      loc[j] = (mloc[base + j] != 0) ? 1 : 0;
      s += loc[j];
    }
    part[tid] = s;
    __syncthreads();
    for (int off = 1; off < 256; off <<= 1) {
      int v = (tid >= off) ? part[tid - off] : 0;
      __syncthreads();
      part[tid] += v;
      __syncthreads();
    }
    int c = (tid > 0) ? part[tid - 1] : 0;
#pragma unroll
    for (int j = 0; j < 16; ++j) {
      c += loc[j];
      int e = (c > 1 ? c : 1) << 3;  // *W=8
      endw[base + j] = e > 64 ? 64 : e;
    }
  } else {
    int* isbool = (int*)shf;
    if (tid == 0) *isbool = 0;
    __syncthreads();
    const unsigned char v = mraw[tid];
    if ((tid & 3) != 0 && v != 0) atomicOr(isbool, 1);
    __syncthreads();
    mk[tid] = (*isbool) ? (int)mraw[tid] : ((const int*)mraw)[tid];
  }
}

// ---------------------------------------------------------------------------
extern "C" void kernel_launch(void* const* d_in, const int* in_sizes, int n_in,
                              void* d_out, int out_size, void* d_ws,
                              size_t ws_size, hipStream_t stream) {
  const float* x = (const float*)d_in[0];
  const float* media = (const float*)d_in[1];
  const unsigned char* mraw = (const unsigned char*)d_in[2];
  const int* mloc = (const int*)d_in[3];
  const float* Wq = (const float*)d_in[4];
  const float* Wkv = (const float*)d_in[5];
  const float* Wout = (const float*)d_in[6];
  const float* gamma = (const float*)d_in[7];
  const float* beta = (const float*)d_in[8];
  float* out = (float*)d_out;

  // xn (bf16, 67MB) lives in d_out scratch; dead before final GEMM overwrites.
  bf16* xn = (bf16*)d_out;

  char* ws = (char*)d_ws;
  size_t off = 0;
  auto carve = [&](size_t bytes) {
    void* p = ws + off;
    off += (bytes + 255) & ~(size_t)255;
    return p;
  };
  bf16* aob = (bf16*)carve((size_t)16384 * 512 * 2);
  bf16* kvb = (bf16*)carve((size_t)256 * 1024 * 2);
  bf16* wqT = (bf16*)carve((size_t)512 * 2048 * 2);
  bf16* wkvT = (bf16*)carve((size_t)1024 * 1024 * 2);
  bf16* woT = (bf16*)carve((size_t)2048 * 512 * 2);
  bf16* medb = (bf16*)carve((size_t)256 * 1024 * 2);
  int* endw = (int*)carve((size_t)4 * 4096 * 4);
  int* mk = (int*)carve(256 * 4);
  (void)ws_size;
  (void)in_sizes;
  (void)n_in;
  (void)out_size;

  // one fused prep pass (LN, 3 weight transposes, media cast, cumsum, mask)
  prep_all<<<18181, 256, 0, stream>>>(x, gamma, beta, xn, Wq, wqT, Wkv, wkvT,
                                      Wout, woT, media, medb, mloc, endw, mraw,
                                      mk);

  // KV projection (small)
  gemm_bt<1><<<dim3(8, 2), 256, 0, stream>>>(medb, wkvT, kvb, 256, 1024, 1024);

  // FUSED Q-projection + attention -> aob (1024 blocks x 256 threads = 4/CU)
  qattn<<<dim3(4, 256), 256, 0, stream>>>(xn, wqT, kvb, mk, endw, aob);

  // output projection (f32 out): 2048 blocks, 16 KB LDS
  gemm_bt<0><<<dim3(16, 128), 256, 0, stream>>>(aob, woT, out, 16384, 2048,
                                                512);
}

// Round 21
// 157.438 us; speedup vs baseline: 1.1358x; 1.1358x over previous
//
#include <hip/hip_runtime.h>
#include <float.h>

typedef __bf16 bf16;
typedef __bf16 bf16x8 __attribute__((ext_vector_type(8)));
typedef float f32x4 __attribute__((ext_vector_type(4)));

#define GAS __attribute__((address_space(1)))
#define LAS __attribute__((address_space(3)))

__device__ __forceinline__ void gload_lds16(const void* g, void* l) {
  __builtin_amdgcn_global_load_lds((const GAS unsigned int*)g, (LAS unsigned int*)l, 16, 0, 0);
}

// ---------------------------------------------------------------------------
// FUSED Q-projection GEMM + attention — 8 waves/block (R17-verified best).
// BM=128 x BN=128 (2 heads), 512 threads (8 waves as 4M x 2N, wave tile
// 32x64), BK=64, ring-2 64KB LDS -> 2 blocks/CU, 4 waves/SIMD.
// Occupancy sweep ledger: 1x8w bad (R8), 2x4w good (R10), 2x8w BEST (R17),
// 4x4w/BK=32 bad (R20).
// ---------------------------------------------------------------------------
__global__ __launch_bounds__(512, 4) void qattn(
    const bf16* __restrict__ xn, const bf16* __restrict__ wqT,
    const bf16* __restrict__ kvb, const int* __restrict__ mk,
    const int* __restrict__ endw, bf16* __restrict__ aob) {
  constexpr int K = 2048;
  __shared__ __align__(16) bf16 Abuf[2][128 * 64];  // 32 KB
  __shared__ __align__(16) bf16 Bbuf[2][128 * 64];  // 32 KB
  const int tid = threadIdx.x, lane = tid & 63;
  const int w = tid >> 6, wr = w >> 1, wc = w & 1;  // 8 waves: 4M x 2N
  const int g = lane >> 4, fr = lane & 15;

  const int gx = gridDim.x;
  int lid = blockIdx.y * gx + blockIdx.x;
  lid = ((lid & 7) << 6) | (lid >> 3);
  const int bx = lid % gx, by = lid / gx;
  const size_t m0 = (size_t)by * 128;
  const int n0 = bx * 128;  // heads 2*bx, 2*bx+1
  const int b = by >> 5;    // batch

  const int nt = K >> 6;  // 32
  const int srow = tid >> 3, sslot = tid & 7;  // 64 rows per 512-thread pass

  f32x4 acc[2][4] = {};

  auto stage = [&](int t) {
    const int s = t & 1;
    const int kt = t << 6;
#pragma unroll
    for (int c = 0; c < 2; ++c) {
      const int r = c * 64 + srow;
      gload_lds16(xn + (m0 + r) * (size_t)K + kt + ((sslot ^ (r & 7)) << 3),
                  &Abuf[s][c * 4096 + tid * 8]);
    }
#pragma unroll
    for (int c = 0; c < 2; ++c) {
      const int r = c * 64 + srow;
      gload_lds16(wqT + (size_t)(n0 + r) * K + kt + ((sslot ^ (r & 7)) << 3),
                  &Bbuf[s][c * 4096 + tid * 8]);
    }
  };
  auto rdA = [&](int s, int mi, int ks) {
    const int r = wr * 32 + mi * 16 + fr;
    return *(const bf16x8*)&Abuf[s][r * 64 + ((((ks << 2) | g) ^ (r & 7)) << 3)];
  };
  auto rdB = [&](int s, int ni, int ks) {
    const int r = wc * 64 + ni * 16 + fr;
    return *(const bf16x8*)&Bbuf[s][r * 64 + ((((ks << 2) | g) ^ (r & 7)) << 3)];
  };
  auto compute = [&](int t) {
    const int s = t & 1;
    bf16x8 bv[4][2];
#pragma unroll
    for (int ni = 0; ni < 4; ++ni)
#pragma unroll
      for (int ks = 0; ks < 2; ++ks) bv[ni][ks] = rdB(s, ni, ks);
    __builtin_amdgcn_s_setprio(1);
#pragma unroll
    for (int mi = 0; mi < 2; ++mi)
#pragma unroll
      for (int ks = 0; ks < 2; ++ks) {
        const bf16x8 av = rdA(s, mi, ks);
#pragma unroll
        for (int ni = 0; ni < 4; ++ni)
          acc[mi][ni] = __builtin_amdgcn_mfma_f32_16x16x32_bf16(
              av, bv[ni][ks], acc[mi][ni], 0, 0, 0);
      }
    __builtin_amdgcn_s_setprio(0);
  };

  stage(0);
  for (int t = 0; t < nt; ++t) {
    __syncthreads();
    if (t + 1 < nt) stage(t + 1);
    compute(t);
  }

  // ======== attention epilogue ========
  __syncthreads();

  bf16* QP = &Abuf[0][0] + w * 2048;  // wave-private [32 rows][64 cols] swz
  bf16* Klds = &Bbuf[0][0];
  bf16* Vlds = &Bbuf[1][0];

#pragma unroll
  for (int mi = 0; mi < 2; ++mi)
#pragma unroll
    for (int ni = 0; ni < 4; ++ni)
#pragma unroll
      for (int rg = 0; rg < 4; ++rg) {
        const int row = mi * 16 + g * 4 + rg, col = ni * 16 + fr;
        QP[row * 64 + (((col >> 3) ^ (row & 7)) << 3) + (col & 7)] =
            (bf16)acc[mi][ni][rg];
      }

#pragma unroll
  for (int j = 0; j < 2; ++j) {
    const int idx = j * 512 + tid;
    const int head = idx >> 9, l = (idx >> 3) & 63, sl = idx & 7;
    gload_lds16(kvb + (size_t)(b * 64 + l) * 1024 + (2 * bx + head) * 64 +
                    ((sl ^ (l & 7)) << 3),
                Klds + (j * 512 + w * 64) * 8);
  }
#pragma unroll
  for (int j = 0; j < 2; ++j) {
    const int idx = j * 512 + tid;
    const int head = idx >> 9, l = (idx >> 3) & 63, sg = idx & 7;
    bf16x8 vv = *(const bf16x8*)&kvb[(size_t)(b * 64 + l) * 1024 + 512 +
                                     (2 * bx + head) * 64 + sg * 8];
#pragma unroll
    for (int e = 0; e < 8; ++e) {
      const int dh = sg * 8 + e;
      Vlds[head * 4096 + dh * 64 + (((l >> 3) ^ (dh & 7)) << 3) + (l & 7)] =
          vv[e];
    }
  }
  asm volatile("s_waitcnt vmcnt(0)" ::: "memory");
  __syncthreads();

  f32x4 sacc[2][4] = {};
#pragma unroll
  for (int ks = 0; ks < 2; ++ks) {
    bf16x8 aq[2], bk[4];
#pragma unroll
    for (int mi = 0; mi < 2; ++mi) {
      const int r = mi * 16 + fr;
      aq[mi] = *(const bf16x8*)&QP[r * 64 + ((((ks << 2) | g) ^ (r & 7)) << 3)];
    }
#pragma unroll
    for (int ni = 0; ni < 4; ++ni) {
      const int l = ni * 16 + fr;
      bk[ni] = *(const bf16x8*)&Klds[wc * 4096 + l * 64 +
                                     ((((ks << 2) | g) ^ (l & 7)) << 3)];
    }
#pragma unroll
    for (int mi = 0; mi < 2; ++mi)
#pragma unroll
      for (int ni = 0; ni < 4; ++ni)
        sacc[mi][ni] = __builtin_amdgcn_mfma_f32_16x16x32_bf16(
            aq[mi], bk[ni], sacc[mi][ni], 0, 0, 0);
  }

#pragma unroll
  for (int mi = 0; mi < 2; ++mi) {
    const int4 ev4 = *(const int4*)&endw[m0 + wr * 32 + mi * 16 + g * 4];
    const int ev[4] = {ev4.x, ev4.y, ev4.z, ev4.w};
    float p[4][4];
#pragma unroll
    for (int ni = 0; ni < 4; ++ni) {
      const int l = ni * 16 + fr;
      const bool mv = (mk[b * 64 + l] != 0);
#pragma unroll
      for (int rg = 0; rg < 4; ++rg)
        p[ni][rg] = (mv && (l < ev[rg])) ? sacc[mi][ni][rg] : -FLT_MAX;
    }
#pragma unroll
    for (int rg = 0; rg < 4; ++rg) {
      float m = fmaxf(fmaxf(p[0][rg], p[1][rg]), fmaxf(p[2][rg], p[3][rg]));
      m = fmaxf(m, __shfl_xor(m, 1));
      m = fmaxf(m, __shfl_xor(m, 2));
      m = fmaxf(m, __shfl_xor(m, 4));
      m = fmaxf(m, __shfl_xor(m, 8));
      float sum = 0.f;
#pragma unroll
      for (int ni = 0; ni < 4; ++ni) {
        p[ni][rg] = __expf(p[ni][rg] - m);
        sum += p[ni][rg];
      }
      sum += __shfl_xor(sum, 1);
      sum += __shfl_xor(sum, 2);
      sum += __shfl_xor(sum, 4);
      sum += __shfl_xor(sum, 8);
      const float inv = 1.f / sum;
#pragma unroll
      for (int ni = 0; ni < 4; ++ni) p[ni][rg] *= inv;
    }
#pragma unroll
    for (int ni = 0; ni < 4; ++ni) {
      const int l = ni * 16 + fr;
#pragma unroll
      for (int rg = 0; rg < 4; ++rg) {
        const int row = mi * 16 + g * 4 + rg;
        QP[row * 64 + (((l >> 3) ^ (row & 7)) << 3) + (l & 7)] =
            (bf16)p[ni][rg];
      }
    }
  }

  f32x4 oacc[2][4] = {};
#pragma unroll
  for (int ks = 0; ks < 2; ++ks) {
    bf16x8 pa[2], bv[4];
#pragma unroll
    for (int mi = 0; mi < 2; ++mi) {
      const int r = mi * 16 + fr;
      pa[mi] = *(const bf16x8*)&QP[r * 64 + ((((ks << 2) | g) ^ (r & 7)) << 3)];
    }
#pragma unroll
    for (int nd = 0; nd < 4; ++nd) {
      const int dh = nd * 16 + fr;
      bv[nd] = *(const bf16x8*)&Vlds[wc * 4096 + dh * 64 +
                                     ((((ks << 2) | g) ^ (dh & 7)) << 3)];
    }
#pragma unroll
    for (int mi = 0; mi < 2; ++mi)
#pragma unroll
      for (int nd = 0; nd < 4; ++nd)
        oacc[mi][nd] = __builtin_amdgcn_mfma_f32_16x16x32_bf16(
            pa[mi], bv[nd], oacc[mi][nd], 0, 0, 0);
  }
#pragma unroll
  for (int mi = 0; mi < 2; ++mi)
#pragma unroll
    for (int nd = 0; nd < 4; ++nd)
#pragma unroll
      for (int rg = 0; rg < 4; ++rg) {
        const size_t t = m0 + wr * 32 + mi * 16 + g * 4 + rg;
        aob[t * 512 + (2 * bx + wc) * 64 + nd * 16 + fr] =
            (bf16)oacc[mi][nd][rg];
      }
}

// ---------------------------------------------------------------------------
// m97-style 128x128 GEMM, BK=32, 16 KB LDS -> multi-block/CU TLP overlap.
// Used for KV projection and the output projection (best measured config).
// ---------------------------------------------------------------------------
template <int OUT_BF16>
__global__ __launch_bounds__(256, 2) void gemm_bt(
    const bf16* __restrict__ A, const bf16* __restrict__ Bt,
    void* __restrict__ Cv, int M, int N, int K) {
  __shared__ bf16 As[128 * 32];
  __shared__ bf16 Bs[128 * 32];
  const int tid = threadIdx.x;
  const int lane = tid & 63, w = tid >> 6;
  const int wr = w >> 1, wc = w & 1;

  const int gx = gridDim.x;
  const int nwg = gx * gridDim.y;
  int lid = blockIdx.y * gx + blockIdx.x;
  {
    const int qq = nwg >> 3, rr = nwg & 7;
    const int xcd = lid & 7, pos = lid >> 3;
    lid = (xcd < rr ? xcd * (qq + 1) : rr * (qq + 1) + (xcd - rr) * qq) + pos;
  }
  const int bx = lid % gx, by = lid / gx;
  const size_t m0 = (size_t)by * 128, n0 = (size_t)bx * 128;

  const int srow = lane >> 2, sslot = lane & 3;
  const int g = lane >> 4, fr = lane & 15;

  f32x4 acc[4][4] = {};

  for (int kt = 0; kt < K; kt += 32) {
    __syncthreads();
#pragma unroll
    for (int j = 0; j < 2; ++j) {
      const int c = 2 * w + j;
      const int r = c * 16 + srow;
      const int ks = (sslot ^ (r & 3)) << 3;
      gload_lds16(A + (m0 + r) * K + kt + ks, &As[c * 512]);
      gload_lds16(Bt + (n0 + r) * K + kt + ks, &Bs[c * 512]);
    }
    __syncthreads();
    bf16x8 av[4], bv[4];
#pragma unroll
    for (int mi = 0; mi < 4; ++mi) {
      const int r = wr * 64 + mi * 16 + fr;
      av[mi] = *(const bf16x8*)&As[r * 32 + ((g ^ (r & 3)) << 3)];
    }
#pragma unroll
    for (int ni = 0; ni < 4; ++ni) {
      const int r = wc * 64 + ni * 16 + fr;
      bv[ni] = *(const bf16x8*)&Bs[r * 32 + ((g ^ (r & 3)) << 3)];
    }
#pragma unroll
    for (int mi = 0; mi < 4; ++mi)
#pragma unroll
      for (int ni = 0; ni < 4; ++ni)
        acc[mi][ni] = __builtin_amdgcn_mfma_f32_16x16x32_bf16(
            av[mi], bv[ni], acc[mi][ni], 0, 0, 0);
  }

#pragma unroll
  for (int mi = 0; mi < 4; ++mi)
#pragma unroll
    for (int ni = 0; ni < 4; ++ni)
#pragma unroll
      for (int rg = 0; rg < 4; ++rg) {
        const size_t row = m0 + wr * 64 + mi * 16 + g * 4 + rg;
        const size_t col = n0 + wc * 64 + ni * 16 + fr;
        if (OUT_BF16)
          ((bf16*)Cv)[row * (size_t)N + col] = (bf16)acc[mi][ni][rg];
        else
          ((float*)Cv)[row * (size_t)N + col] = acc[mi][ni][rg];
      }
}

// ---------------------------------------------------------------------------
// Coalesced 64x64 LDS-tiled transpose: dst[C][R] = src[R][C] * scale (bf16)
// ---------------------------------------------------------------------------
__device__ __forceinline__ void transp64(const float* __restrict__ src,
                                         bf16* __restrict__ dst, int R, int C,
                                         float scale, int tile, float* lds) {
  const int tilesC = C >> 6;
  const int tr = tile / tilesC, tc = tile % tilesC;
  const int r0 = tr << 6, c0 = tc << 6;
  const int tid = threadIdx.x;
  const int lr = tid >> 6, lc = tid & 63;
#pragma unroll
  for (int j = 0; j < 16; ++j) {
    const int r = j * 4 + lr;
    lds[r * 65 + lc] = src[(size_t)(r0 + r) * C + c0 + lc];
  }
  __syncthreads();
#pragma unroll
  for (int j = 0; j < 16; ++j) {
    const int rr = j * 4 + lr;  // dst row = src col
    dst[(size_t)(c0 + rr) * R + r0 + lc] = (bf16)(lds[lc * 65 + rr] * scale);
  }
}

// ---------------------------------------------------------------------------
// Mega prep kernel: one launch, block-range partitioned (baseline layout).
// ---------------------------------------------------------------------------
__global__ __launch_bounds__(256) void prep_all(
    const float* __restrict__ x, const float* __restrict__ gamma,
    const float* __restrict__ beta, bf16* __restrict__ xn,
    const float* __restrict__ Wq, bf16* __restrict__ wqT,
    const float* __restrict__ Wkv, bf16* __restrict__ wkvT,
    const float* __restrict__ Wout, bf16* __restrict__ woT,
    const float* __restrict__ media, bf16* __restrict__ medb,
    const int* __restrict__ mloc, int* __restrict__ endw,
    const unsigned char* __restrict__ mraw, int* __restrict__ mk) {
  __shared__ float shf[64 * 65];
  const int blk = blockIdx.x, tid = threadIdx.x;

  if (blk < 16384) {
    const size_t base = (size_t)blk * 2048 + tid * 8;
    f32x4 v0 = *(const f32x4*)(x + base);
    f32x4 v1 = *(const f32x4*)(x + base + 4);
    float s = 0.f, q2 = 0.f;
#pragma unroll
    for (int j = 0; j < 4; ++j) {
      s += v0[j] + v1[j];
      q2 += v0[j] * v0[j] + v1[j] * v1[j];
    }
    for (int off = 32; off > 0; off >>= 1) {
      s += __shfl_down(s, off);
      q2 += __shfl_down(q2, off);
    }
    const int lane = tid & 63, wv = tid >> 6;
    if (lane == 0) { shf[wv] = s; shf[4 + wv] = q2; }
    __syncthreads();
    s = shf[0] + shf[1] + shf[2] + shf[3];
    q2 = shf[4] + shf[5] + shf[6] + shf[7];
    const float mu = s * (1.f / 2048.f);
    const float var = q2 * (1.f / 2048.f) - mu * mu;
    const float rs = rsqrtf(var + 1e-5f);
    f32x4 g0 = *(const f32x4*)(gamma + tid * 8);
    f32x4 g1 = *(const f32x4*)(gamma + tid * 8 + 4);
    f32x4 b0 = *(const f32x4*)(beta + tid * 8);
    f32x4 b1 = *(const f32x4*)(beta + tid * 8 + 4);
    bf16x8 o;
#pragma unroll
    for (int j = 0; j < 4; ++j) {
      o[j] = (bf16)((v0[j] - mu) * rs * g0[j] + b0[j]);
      o[4 + j] = (bf16)((v1[j] - mu) * rs * g1[j] + b1[j]);
    }
    *(bf16x8*)(xn + base) = o;
  } else if (blk < 16640) {
    transp64(Wq, wqT, 2048, 512, 0.125f, blk - 16384, shf);
  } else if (blk < 16896) {
    transp64(Wkv, wkvT, 1024, 1024, 1.f, blk - 16640, shf);
  } else if (blk < 17152) {
    transp64(Wout, woT, 512, 2048, 1.f, blk - 16896, shf);
  } else if (blk < 18176) {
    const int i = (blk - 17152) * 256 + tid;
    medb[i] = (bf16)media[i];
  } else if (blk < 18180) {
    int* part = (int*)shf;
    const int b = blk - 18176;
    int loc[16];
    int s = 0;
    const int base = b * 4096 + tid * 16;
#pragma unroll
    for (int j = 0; j < 16; ++j) {
      loc[j] = (mloc[base + j] != 0) ? 1 : 0;
      s += loc[j];
    }
    part[tid] = s;
    __syncthreads();
    for (int off = 1; off < 256; off <<= 1) {
      int v = (tid >= off) ? part[tid - off] : 0;
      __syncthreads();
      part[tid] += v;
      __syncthreads();
    }
    int c = (tid > 0) ? part[tid - 1] : 0;
#pragma unroll
    for (int j = 0; j < 16; ++j) {
      c += loc[j];
      int e = (c > 1 ? c : 1) << 3;  // *W=8
      endw[base + j] = e > 64 ? 64 : e;
    }
  } else {
    int* isbool = (int*)shf;
    if (tid == 0) *isbool = 0;
    __syncthreads();
    const unsigned char v = mraw[tid];
    if ((tid & 3) != 0 && v != 0) atomicOr(isbool, 1);
    __syncthreads();
    mk[tid] = (*isbool) ? (int)mraw[tid] : ((const int*)mraw)[tid];
  }
}

// ---------------------------------------------------------------------------
extern "C" void kernel_launch(void* const* d_in, const int* in_sizes, int n_in,
                              void* d_out, int out_size, void* d_ws,
                              size_t ws_size, hipStream_t stream) {
  const float* x = (const float*)d_in[0];
  const float* media = (const float*)d_in[1];
  const unsigned char* mraw = (const unsigned char*)d_in[2];
  const int* mloc = (const int*)d_in[3];
  const float* Wq = (const float*)d_in[4];
  const float* Wkv = (const float*)d_in[5];
  const float* Wout = (const float*)d_in[6];
  const float* gamma = (const float*)d_in[7];
  const float* beta = (const float*)d_in[8];
  float* out = (float*)d_out;

  // xn (bf16, 67MB) lives in d_out scratch; dead before final GEMM overwrites.
  bf16* xn = (bf16*)d_out;

  char* ws = (char*)d_ws;
  size_t off = 0;
  auto carve = [&](size_t bytes) {
    void* p = ws + off;
    off += (bytes + 255) & ~(size_t)255;
    return p;
  };
  bf16* aob = (bf16*)carve((size_t)16384 * 512 * 2);
  bf16* kvb = (bf16*)carve((size_t)256 * 1024 * 2);
  bf16* wqT = (bf16*)carve((size_t)512 * 2048 * 2);
  bf16* wkvT = (bf16*)carve((size_t)1024 * 1024 * 2);
  bf16* woT = (bf16*)carve((size_t)2048 * 512 * 2);
  bf16* medb = (bf16*)carve((size_t)256 * 1024 * 2);
  int* endw = (int*)carve((size_t)4 * 4096 * 4);
  int* mk = (int*)carve(256 * 4);
  (void)ws_size;
  (void)in_sizes;
  (void)n_in;
  (void)out_size;

  // one fused prep pass (LN, 3 weight transposes, media cast, cumsum, mask)
  prep_all<<<18181, 256, 0, stream>>>(x, gamma, beta, xn, Wq, wqT, Wkv, wkvT,
                                      Wout, woT, media, medb, mloc, endw, mraw,
                                      mk);

  // KV projection (small)
  gemm_bt<1><<<dim3(8, 2), 256, 0, stream>>>(medb, wkvT, kvb, 256, 1024, 1024);

  // FUSED Q-projection + attention -> aob (512 blocks x 512 threads = 2/CU,
  // 4 waves/SIMD)
  qattn<<<dim3(4, 128), 512, 0, stream>>>(xn, wqT, kvb, mk, endw, aob);

  // output projection (f32 out): 2048 blocks, 16 KB LDS
  gemm_bt<0><<<dim3(16, 128), 256, 0, stream>>>(aob, woT, out, 16384, 2048,
                                                512);
}